// Round 1
// baseline (378.046 us; speedup 1.0000x reference)
//
#include <hip/hip_runtime.h>
#include <hip/hip_bf16.h>

#define DEVFN __device__ __forceinline__

typedef __attribute__((ext_vector_type(8))) __bf16 bf16x8;
typedef __attribute__((ext_vector_type(4))) float f32x4;

constexpr int E   = 512;   // embed
constexpr int S   = 4096;  // seq len
constexpr int NH  = 8;     // heads
constexpr int HD  = 64;    // head dim
constexpr int RT  = 8192;  // B * S rows

DEVFN unsigned short f2bf(float f) {
  union { float f; unsigned int u; } v; v.f = f;
  unsigned int u = v.u;
  return (unsigned short)((u + 0x7fffu + ((u >> 16) & 1u)) >> 16);
}

DEVFN f32x4 mfma16(bf16x8 a, bf16x8 b, f32x4 c) {
  return __builtin_amdgcn_mfma_f32_16x16x32_bf16(a, b, c, 0, 0, 0);
}

// ---------------------------------------------------------------------------
// GEMM (NT): out[r, n] = (sum_k X[r,k] * W[n,k] + bias[n]) * scale
// X: [8192, 512] (fp32 or bf16-as-ushort), W: [512,512] fp32 row-major.
// Tile 128x64, BK=64, 256 threads (4 waves as 2x2 over 64x32 sub-tiles).
// LDS stride 72 elems (144 B): keeps 16B alignment for b128 ops, rotates
// banks by 4/row -> 2-way max (free per m136).
// ---------------------------------------------------------------------------
template<typename TIN, bool OUT_F32>
__global__ __launch_bounds__(256) void gemm_nt(const TIN* __restrict__ X,
                                               const float* __restrict__ W,
                                               const float* __restrict__ bias,
                                               void* __restrict__ outp,
                                               float scale) {
  __shared__ unsigned short Al[128][72];
  __shared__ unsigned short Bl[64][72];
  const int bm = blockIdx.x >> 3, bn = blockIdx.x & 7;  // 64 x 8 blocks
  const int tid = threadIdx.x;
  const int w = tid >> 6, lane = tid & 63;
  const int g = lane >> 4, ln = lane & 15;
  const int wm = w >> 1, wn = w & 1;
  const int r0 = bm * 128, n0 = bn * 64;

  const int arow = tid >> 1, ac0 = (tid & 1) * 32;  // A: 2 thr/row, 32 elems each
  const int brow = tid >> 2, bc0 = (tid & 3) * 16;  // B: 4 thr/row, 16 elems each

  f32x4 acc[4][2] = {};

  for (int k0 = 0; k0 < E; k0 += 64) {
    // ---- stage A tile [128][64] ----
    if constexpr (sizeof(TIN) == 4) {
      const float* src = (const float*)X + (size_t)(r0 + arow) * E + k0 + ac0;
      unsigned short t[32];
      #pragma unroll
      for (int q = 0; q < 8; ++q) {
        float4 fv = *(const float4*)(src + q * 4);
        t[q*4+0] = f2bf(fv.x); t[q*4+1] = f2bf(fv.y);
        t[q*4+2] = f2bf(fv.z); t[q*4+3] = f2bf(fv.w);
      }
      #pragma unroll
      for (int q = 0; q < 4; ++q)
        *(uint4*)&Al[arow][ac0 + q*8] = *(const uint4*)&t[q*8];
    } else {
      const unsigned short* src = (const unsigned short*)X + (size_t)(r0 + arow) * E + k0 + ac0;
      #pragma unroll
      for (int q = 0; q < 4; ++q)
        *(uint4*)&Al[arow][ac0 + q*8] = *(const uint4*)(src + q*8);
    }
    // ---- stage B tile [64][64] from W (fp32) ----
    {
      const float* src = W + (size_t)(n0 + brow) * E + k0 + bc0;
      unsigned short t[16];
      #pragma unroll
      for (int q = 0; q < 4; ++q) {
        float4 fv = *(const float4*)(src + q * 4);
        t[q*4+0] = f2bf(fv.x); t[q*4+1] = f2bf(fv.y);
        t[q*4+2] = f2bf(fv.z); t[q*4+3] = f2bf(fv.w);
      }
      #pragma unroll
      for (int q = 0; q < 2; ++q)
        *(uint4*)&Bl[brow][bc0 + q*8] = *(const uint4*)&t[q*8];
    }
    __syncthreads();

    #pragma unroll
    for (int kk = 0; kk < 2; ++kk) {
      bf16x8 af[4], bfv[2];
      #pragma unroll
      for (int i = 0; i < 4; ++i)
        af[i] = *(const bf16x8*)&Al[wm*64 + i*16 + ln][kk*32 + 8*g];
      #pragma unroll
      for (int j = 0; j < 2; ++j)
        bfv[j] = *(const bf16x8*)&Bl[wn*32 + j*16 + ln][kk*32 + 8*g];
      #pragma unroll
      for (int i = 0; i < 4; ++i)
        #pragma unroll
        for (int j = 0; j < 2; ++j)
          acc[i][j] = mfma16(af[i], bfv[j], acc[i][j]);
    }
    __syncthreads();
  }

  // epilogue: C/D layout col=lane&15, row=4*(lane>>4)+reg (HW-verified)
  #pragma unroll
  for (int j = 0; j < 2; ++j) {
    const int gcol = n0 + wn*32 + j*16 + ln;
    const float bv = bias[gcol];
    #pragma unroll
    for (int i = 0; i < 4; ++i) {
      const int gr = r0 + wm*64 + i*16 + 4*g;
      #pragma unroll
      for (int r = 0; r < 4; ++r) {
        const float v = (acc[i][j][r] + bv) * scale;
        if constexpr (OUT_F32)
          ((float*)outp)[(size_t)(gr + r) * E + gcol] = v;
        else
          ((unsigned short*)outp)[(size_t)(gr + r) * E + gcol] = f2bf(v);
      }
    }
  }
}

// ---------------------------------------------------------------------------
// Flash attention forward. qh is pre-scaled by 1/sqrt(512).
// Block: one (b, h, 64-row q-tile). 4 waves x 16 q-rows. KV tiles of 64.
// K in LDS row-major [t][d]; V transposed [d][t]; P via per-wave LDS.
// ---------------------------------------------------------------------------
__global__ __launch_bounds__(256) void attn_fwd(const unsigned short* __restrict__ qh,
                                                const unsigned short* __restrict__ kh,
                                                const unsigned short* __restrict__ vh,
                                                unsigned short* __restrict__ cc) {
  __shared__ unsigned short K_lds[64][72];     // [t][d]
  __shared__ unsigned short V_lds[64][72];     // [d][t] (transposed)
  __shared__ unsigned short P_lds[4][16][72];  // per-wave [qrow][t]

  // XCD-bijective swizzle (1024 blocks, 1024 % 8 == 0): each XCD gets a
  // contiguous chunk = 2 (b,h) pairs of KV (2 MB) -> fits its 4 MB L2.
  const int bid = blockIdx.x;
  const int swz = (bid & 7) * 128 + (bid >> 3);
  const int bh = swz >> 6, qt = swz & 63;
  const int b = bh >> 3, h = bh & 7;

  const int tid = threadIdx.x;
  const int w = tid >> 6, lane = tid & 63;
  const int g = lane >> 4, ln = lane & 15;

  const size_t base = (size_t)b * S * E + (size_t)h * HD;
  const unsigned short* qb = qh + base;
  const unsigned short* kb = kh + base;
  const unsigned short* vb = vh + base;
  const int q0 = qt * 64 + w * 16;

  // Q fragments (row = ln, k = kk*32 + 8g + j), held in regs for the kernel
  bf16x8 qf[2];
  #pragma unroll
  for (int kk = 0; kk < 2; ++kk)
    qf[kk] = *(const bf16x8*)(qb + (size_t)(q0 + ln) * E + kk*32 + 8*g);

  f32x4 oacc[4] = {};
  float mr[4], lr[4] = {};
  #pragma unroll
  for (int r = 0; r < 4; ++r) mr[r] = -__builtin_inff();

  const int krow = tid >> 2, kc0 = (tid & 3) * 16;

  for (int it = 0; it < S / 64; ++it) {
    const int t0 = it * 64;
    // ---- stage K row-major ----
    {
      const unsigned short* src = kb + (size_t)(t0 + krow) * E + kc0;
      uint4 a0 = *(const uint4*)src;
      uint4 a1 = *(const uint4*)(src + 8);
      *(uint4*)&K_lds[krow][kc0]     = a0;
      *(uint4*)&K_lds[krow][kc0 + 8] = a1;
    }
    // ---- stage V transposed ----
    #pragma unroll
    for (int p = 0; p < 2; ++p) {
      const int c = tid + p * 256;
      const int vrow = c & 63, vc0 = (c >> 6) * 8;
      uint4 dv = *(const uint4*)(vb + (size_t)(t0 + vrow) * E + vc0);
      const unsigned short* ev = (const unsigned short*)&dv;
      #pragma unroll
      for (int j = 0; j < 8; ++j)
        V_lds[vc0 + j][vrow] = ev[j];
    }
    __syncthreads();

    // ---- S = Q * K^T (scaled already) ----
    f32x4 sacc[4] = {};
    #pragma unroll
    for (int kk = 0; kk < 2; ++kk) {
      #pragma unroll
      for (int nt = 0; nt < 4; ++nt) {
        bf16x8 kf = *(const bf16x8*)&K_lds[nt*16 + ln][kk*32 + 8*g];
        sacc[nt] = mfma16(qf[kk], kf, sacc[nt]);
      }
    }

    // ---- online softmax (rows r = 4g+reg; cols spread over 16-lane group) ----
    float tmax[4];
    #pragma unroll
    for (int r = 0; r < 4; ++r)
      tmax[r] = fmaxf(fmaxf(sacc[0][r], sacc[1][r]), fmaxf(sacc[2][r], sacc[3][r]));
    #pragma unroll
    for (int d = 1; d < 16; d <<= 1)
      #pragma unroll
      for (int r = 0; r < 4; ++r)
        tmax[r] = fmaxf(tmax[r], __shfl_xor(tmax[r], d, 64));

    float fr[4], rs[4] = {};
    #pragma unroll
    for (int r = 0; r < 4; ++r) {
      const float mn = fmaxf(mr[r], tmax[r]);
      fr[r] = exp2f((mr[r] - mn) * 1.4426950408889634f);
      mr[r] = mn;
    }
    #pragma unroll
    for (int nt = 0; nt < 4; ++nt)
      #pragma unroll
      for (int r = 0; r < 4; ++r) {
        const float p = exp2f((sacc[nt][r] - mr[r]) * 1.4426950408889634f);
        sacc[nt][r] = p;
        rs[r] += p;
      }
    #pragma unroll
    for (int d = 1; d < 16; d <<= 1)
      #pragma unroll
      for (int r = 0; r < 4; ++r)
        rs[r] += __shfl_xor(rs[r], d, 64);
    #pragma unroll
    for (int r = 0; r < 4; ++r) lr[r] = lr[r] * fr[r] + rs[r];
    #pragma unroll
    for (int dt = 0; dt < 4; ++dt)
      #pragma unroll
      for (int r = 0; r < 4; ++r) oacc[dt][r] *= fr[r];

    // ---- P -> per-wave LDS (layout turn: C-layout -> A-fragment layout) ----
    #pragma unroll
    for (int nt = 0; nt < 4; ++nt)
      #pragma unroll
      for (int r = 0; r < 4; ++r)
        P_lds[w][4*g + r][nt*16 + ln] = f2bf(sacc[nt][r]);

    // ---- O += P * V ----
    bf16x8 pa0 = *(const bf16x8*)&P_lds[w][ln][8*g];
    bf16x8 pa1 = *(const bf16x8*)&P_lds[w][ln][32 + 8*g];
    #pragma unroll
    for (int dt = 0; dt < 4; ++dt) {
      bf16x8 v0 = *(const bf16x8*)&V_lds[dt*16 + ln][8*g];
      oacc[dt] = mfma16(pa0, v0, oacc[dt]);
      bf16x8 v1 = *(const bf16x8*)&V_lds[dt*16 + ln][32 + 8*g];
      oacc[dt] = mfma16(pa1, v1, oacc[dt]);
    }
    __syncthreads();
  }

  // ---- epilogue: normalize and store concat[b, s, h*64+d] as bf16 ----
  #pragma unroll
  for (int dt = 0; dt < 4; ++dt)
    #pragma unroll
    for (int r = 0; r < 4; ++r) {
      const float v = oacc[dt][r] / lr[r];
      const int row = q0 + 4*g + r;
      const int col = h*HD + dt*16 + ln;
      cc[(size_t)(b*S + row) * E + col] = f2bf(v);
    }
}

// ---------------------------------------------------------------------------
extern "C" void kernel_launch(void* const* d_in, const int* in_sizes, int n_in,
                              void* d_out, int out_size, void* d_ws, size_t ws_size,
                              hipStream_t stream) {
  const float* q  = (const float*)d_in[0];
  const float* k  = (const float*)d_in[1];
  const float* v  = (const float*)d_in[2];
  const float* Wq = (const float*)d_in[3];
  const float* bq = (const float*)d_in[4];
  const float* Wk = (const float*)d_in[5];
  const float* bk = (const float*)d_in[6];
  const float* Wv = (const float*)d_in[7];
  const float* bv = (const float*)d_in[8];
  const float* Wo = (const float*)d_in[9];
  const float* bo = (const float*)d_in[10];
  float* out = (float*)d_out;

  // ws layout: qh | kh | vh | concat, each 8192*512 bf16 = 8 MB (32 MB total)
  unsigned short* qh = (unsigned short*)d_ws;
  unsigned short* kh = qh + (size_t)RT * E;
  unsigned short* vh = kh + (size_t)RT * E;
  unsigned short* cc = vh + (size_t)RT * E;

  const float qscale = 0.04419417382415922f;  // 1/sqrt(512), folded into Q proj

  gemm_nt<float, false><<<dim3(512), dim3(256), 0, stream>>>(q, Wq, bq, qh, qscale);
  gemm_nt<float, false><<<dim3(512), dim3(256), 0, stream>>>(k, Wk, bk, kh, 1.0f);
  gemm_nt<float, false><<<dim3(512), dim3(256), 0, stream>>>(v, Wv, bv, vh, 1.0f);
  attn_fwd<<<dim3(1024), dim3(256), 0, stream>>>(qh, kh, vh, cc);
  gemm_nt<unsigned short, true><<<dim3(512), dim3(256), 0, stream>>>(cc, Wo, bo, out, 1.0f);
}

// Round 2
// 301.985 us; speedup vs baseline: 1.2519x; 1.2519x over previous
//
#include <hip/hip_runtime.h>
#include <hip/hip_bf16.h>

#define DEVFN __device__ __forceinline__

typedef __attribute__((ext_vector_type(8))) __bf16 bf16x8;
typedef __attribute__((ext_vector_type(4))) float f32x4;

constexpr int E   = 512;   // embed
constexpr int S   = 4096;  // seq len
constexpr int NH  = 8;     // heads
constexpr int HD  = 64;    // head dim
constexpr int RT  = 8192;  // B * S rows

DEVFN unsigned short f2bf(float f) {
  union { float f; unsigned int u; } v; v.f = f;
  unsigned int u = v.u;
  return (unsigned short)((u + 0x7fffu + ((u >> 16) & 1u)) >> 16);
}

DEVFN f32x4 mfma16(bf16x8 a, bf16x8 b, f32x4 c) {
  return __builtin_amdgcn_mfma_f32_16x16x32_bf16(a, b, c, 0, 0, 0);
}

// ---------------------------------------------------------------------------
// GEMM (NT): out[r, n] = (sum_k X[r,k] * W[n,k] + bias[n]) * scale
// OMODE: 0 = bf16 row-major [RT][E], 1 = f32 row-major, 2 = bf16 transposed
// per batch: vhT[b][n][s]  (n = h*64+d), i.e. ((b*E + n)*S + s).
// ---------------------------------------------------------------------------
template<typename TIN, int OMODE>
__global__ __launch_bounds__(256) void gemm_nt(const TIN* __restrict__ X,
                                               const float* __restrict__ W,
                                               const float* __restrict__ bias,
                                               void* __restrict__ outp,
                                               float scale) {
  __shared__ unsigned short Al[128][72];
  __shared__ unsigned short Bl[64][72];
  const int bm = blockIdx.x >> 3, bn = blockIdx.x & 7;  // 64 x 8 blocks
  const int tid = threadIdx.x;
  const int w = tid >> 6, lane = tid & 63;
  const int g = lane >> 4, ln = lane & 15;
  const int wm = w >> 1, wn = w & 1;
  const int r0 = bm * 128, n0 = bn * 64;

  const int arow = tid >> 1, ac0 = (tid & 1) * 32;  // A: 2 thr/row, 32 elems each
  const int brow = tid >> 2, bc0 = (tid & 3) * 16;  // B: 4 thr/row, 16 elems each

  f32x4 acc[4][2] = {};

  for (int k0 = 0; k0 < E; k0 += 64) {
    // ---- stage A tile [128][64] ----
    if constexpr (sizeof(TIN) == 4) {
      const float* src = (const float*)X + (size_t)(r0 + arow) * E + k0 + ac0;
      unsigned short t[32];
      #pragma unroll
      for (int q = 0; q < 8; ++q) {
        float4 fv = *(const float4*)(src + q * 4);
        t[q*4+0] = f2bf(fv.x); t[q*4+1] = f2bf(fv.y);
        t[q*4+2] = f2bf(fv.z); t[q*4+3] = f2bf(fv.w);
      }
      #pragma unroll
      for (int q = 0; q < 4; ++q)
        *(uint4*)&Al[arow][ac0 + q*8] = *(const uint4*)&t[q*8];
    } else {
      const unsigned short* src = (const unsigned short*)X + (size_t)(r0 + arow) * E + k0 + ac0;
      #pragma unroll
      for (int q = 0; q < 4; ++q)
        *(uint4*)&Al[arow][ac0 + q*8] = *(const uint4*)(src + q*8);
    }
    // ---- stage B tile [64][64] from W (fp32) ----
    {
      const float* src = W + (size_t)(n0 + brow) * E + k0 + bc0;
      unsigned short t[16];
      #pragma unroll
      for (int q = 0; q < 4; ++q) {
        float4 fv = *(const float4*)(src + q * 4);
        t[q*4+0] = f2bf(fv.x); t[q*4+1] = f2bf(fv.y);
        t[q*4+2] = f2bf(fv.z); t[q*4+3] = f2bf(fv.w);
      }
      #pragma unroll
      for (int q = 0; q < 2; ++q)
        *(uint4*)&Bl[brow][bc0 + q*8] = *(const uint4*)&t[q*8];
    }
    __syncthreads();

    #pragma unroll
    for (int kk = 0; kk < 2; ++kk) {
      bf16x8 af[4], bfv[2];
      #pragma unroll
      for (int i = 0; i < 4; ++i)
        af[i] = *(const bf16x8*)&Al[wm*64 + i*16 + ln][kk*32 + 8*g];
      #pragma unroll
      for (int j = 0; j < 2; ++j)
        bfv[j] = *(const bf16x8*)&Bl[wn*32 + j*16 + ln][kk*32 + 8*g];
      #pragma unroll
      for (int i = 0; i < 4; ++i)
        #pragma unroll
        for (int j = 0; j < 2; ++j)
          acc[i][j] = mfma16(af[i], bfv[j], acc[i][j]);
    }
    __syncthreads();
  }

  // epilogue: C/D layout col=lane&15, row=4*(lane>>4)+reg (HW-verified)
  #pragma unroll
  for (int j = 0; j < 2; ++j) {
    const int gcol = n0 + wn*32 + j*16 + ln;
    const float bv = bias[gcol];
    #pragma unroll
    for (int i = 0; i < 4; ++i) {
      const int gr = r0 + wm*64 + i*16 + 4*g;
      #pragma unroll
      for (int r = 0; r < 4; ++r) {
        const float v = (acc[i][j][r] + bv) * scale;
        if constexpr (OMODE == 1)
          ((float*)outp)[(size_t)(gr + r) * E + gcol] = v;
        else if constexpr (OMODE == 0)
          ((unsigned short*)outp)[(size_t)(gr + r) * E + gcol] = f2bf(v);
        else  // transposed per batch: [(b*E + gcol)][s]
          ((unsigned short*)outp)[((size_t)((gr + r) >> 12) * E + gcol) * S + ((gr + r) & (S - 1))] = f2bf(v);
      }
    }
  }
}

// ---------------------------------------------------------------------------
// Flash attention, swapped-QK^T layout. qh is pre-scaled by log2(e)/sqrt(512)
// so softmax runs in base-2 domain. V comes in pre-transposed (vhT[b][n][s]).
// Block: (b, h, 128-row q-tile). 4 waves x 32 q-rows. KV tiles of 64.
// Swapped QK^T: mfma(K,Q) -> lane(g,ln) holds scores for q=ln, t=nt*16+4g+r.
// Row reductions are in-lane + 2 shfl_xor; P stored t-contiguous (b64 writes).
// ---------------------------------------------------------------------------
__global__ __launch_bounds__(256) void attn_fwd(const unsigned short* __restrict__ qh,
                                                const unsigned short* __restrict__ kh,
                                                const unsigned short* __restrict__ vhT,
                                                unsigned short* __restrict__ cc) {
  __shared__ unsigned short K_lds[64][72];   // [t][d]
  __shared__ unsigned short V_lds[64][72];   // [d][t]  (from vhT, no transpose)
  __shared__ unsigned short P_lds[4][32][72];// per-wave [q][t]

  // XCD-bijective swizzle: 512 blocks, 64 per XCD = 2 heads (2MB KV) per L2.
  const int bid = blockIdx.x;
  const int swz = (bid & 7) * 64 + (bid >> 3);
  const int bh = swz >> 5, qt = swz & 31;
  const int b = bh >> 3, h = bh & 7;

  const int tid = threadIdx.x;
  const int w = tid >> 6, lane = tid & 63;
  const int g = lane >> 4, ln = lane & 15;

  const unsigned short* qb = qh + (size_t)b * S * E + h * HD;
  const unsigned short* kb = kh + (size_t)b * S * E + h * HD;
  const unsigned short* vbT = vhT + ((size_t)b * E + h * HD) * S;
  const int q0 = qt * 128 + w * 32;

  // Q fragments: [qi][kk], row = q0+qi*16+ln, k = kk*32+8g+j
  bf16x8 qf[2][2];
  #pragma unroll
  for (int qi = 0; qi < 2; ++qi)
    #pragma unroll
    for (int kk = 0; kk < 2; ++kk)
      qf[qi][kk] = *(const bf16x8*)(qb + (size_t)(q0 + qi*16 + ln) * E + kk*32 + 8*g);

  f32x4 oacc[2][4] = {};
  float ml[2], ll[2] = {};
  ml[0] = ml[1] = -__builtin_inff();

  const int srow = tid >> 2, sc0 = (tid & 3) * 16;  // staging: 4 thr/row

  for (int it = 0; it < S / 64; ++it) {
    const int t0 = it * 64;
    // ---- stage K [t][d] and V^T [d][t], both vectorized ----
    {
      const unsigned short* ks = kb + (size_t)(t0 + srow) * E + sc0;
      uint4 k0 = *(const uint4*)ks;
      uint4 k1 = *(const uint4*)(ks + 8);
      const unsigned short* vs = vbT + (size_t)srow * S + t0 + sc0;
      uint4 v0 = *(const uint4*)vs;
      uint4 v1 = *(const uint4*)(vs + 8);
      *(uint4*)&K_lds[srow][sc0]     = k0;
      *(uint4*)&K_lds[srow][sc0 + 8] = k1;
      *(uint4*)&V_lds[srow][sc0]     = v0;
      *(uint4*)&V_lds[srow][sc0 + 8] = v1;
    }
    __syncthreads();

    // ---- QK^T swapped: sc[qi][nt], lane holds q=ln(+qi*16), t=nt*16+4g+r ----
    f32x4 sc[2][4] = {};
    #pragma unroll
    for (int nt = 0; nt < 4; ++nt) {
      bf16x8 k0 = *(const bf16x8*)&K_lds[nt*16 + ln][8*g];
      bf16x8 k1 = *(const bf16x8*)&K_lds[nt*16 + ln][32 + 8*g];
      #pragma unroll
      for (int qi = 0; qi < 2; ++qi) {
        sc[qi][nt] = mfma16(k0, qf[qi][0], sc[qi][nt]);
        sc[qi][nt] = mfma16(k1, qf[qi][1], sc[qi][nt]);
      }
    }

    // ---- online softmax (base-2 domain), in-lane over 16 t + 2 shfl ----
    float fr[2];
    #pragma unroll
    for (int qi = 0; qi < 2; ++qi) {
      float m01 = fmaxf(fmaxf(sc[qi][0][0], sc[qi][0][1]), fmaxf(sc[qi][0][2], sc[qi][0][3]));
      float m23 = fmaxf(fmaxf(sc[qi][1][0], sc[qi][1][1]), fmaxf(sc[qi][1][2], sc[qi][1][3]));
      float m45 = fmaxf(fmaxf(sc[qi][2][0], sc[qi][2][1]), fmaxf(sc[qi][2][2], sc[qi][2][3]));
      float m67 = fmaxf(fmaxf(sc[qi][3][0], sc[qi][3][1]), fmaxf(sc[qi][3][2], sc[qi][3][3]));
      float tm = fmaxf(fmaxf(m01, m23), fmaxf(m45, m67));
      tm = fmaxf(tm, __shfl_xor(tm, 16));
      tm = fmaxf(tm, __shfl_xor(tm, 32));
      const float mn = fmaxf(ml[qi], tm);
      fr[qi] = exp2f(ml[qi] - mn);
      ml[qi] = mn;
      float rs = 0.f;
      #pragma unroll
      for (int nt = 0; nt < 4; ++nt) {
        #pragma unroll
        for (int r = 0; r < 4; ++r) {
          const float p = exp2f(sc[qi][nt][r] - mn);
          sc[qi][nt][r] = p;
          rs += p;
        }
      }
      rs += __shfl_xor(rs, 16);
      rs += __shfl_xor(rs, 32);
      ll[qi] = ll[qi] * fr[qi] + rs;
      // ---- P -> LDS, t-contiguous b64 packed writes ----
      #pragma unroll
      for (int nt = 0; nt < 4; ++nt) {
        unsigned int lo = (unsigned int)f2bf(sc[qi][nt][0]) | ((unsigned int)f2bf(sc[qi][nt][1]) << 16);
        unsigned int hi = (unsigned int)f2bf(sc[qi][nt][2]) | ((unsigned int)f2bf(sc[qi][nt][3]) << 16);
        uint2 pk; pk.x = lo; pk.y = hi;
        *(uint2*)&P_lds[w][qi*16 + ln][nt*16 + 4*g] = pk;
      }
    }

    // ---- rescale O by fr (relayout q=ln -> q=4g+r via shfl) ----
    #pragma unroll
    for (int qi = 0; qi < 2; ++qi)
      #pragma unroll
      for (int r = 0; r < 4; ++r) {
        const float fro = __shfl(fr[qi], 4*g + r);
        #pragma unroll
        for (int dt = 0; dt < 4; ++dt)
          oacc[qi][dt][r] *= fro;
      }

    // ---- O += P * V ----
    #pragma unroll
    for (int kk = 0; kk < 2; ++kk) {
      bf16x8 pa0 = *(const bf16x8*)&P_lds[w][ln]     [kk*32 + 8*g];
      bf16x8 pa1 = *(const bf16x8*)&P_lds[w][16 + ln][kk*32 + 8*g];
      #pragma unroll
      for (int dt = 0; dt < 4; ++dt) {
        bf16x8 vf = *(const bf16x8*)&V_lds[dt*16 + ln][kk*32 + 8*g];
        oacc[0][dt] = mfma16(pa0, vf, oacc[0][dt]);
        oacc[1][dt] = mfma16(pa1, vf, oacc[1][dt]);
      }
    }
    __syncthreads();
  }

  // ---- epilogue: normalize, store concat[b,s,h*64+d] bf16 ----
  #pragma unroll
  for (int qi = 0; qi < 2; ++qi)
    #pragma unroll
    for (int r = 0; r < 4; ++r) {
      const float lo = __shfl(ll[qi], 4*g + r);
      const float inv = 1.0f / lo;
      const int row = q0 + qi*16 + 4*g + r;
      #pragma unroll
      for (int dt = 0; dt < 4; ++dt) {
        const int col = h*HD + dt*16 + ln;
        cc[(size_t)(b*S + row) * E + col] = f2bf(oacc[qi][dt][r] * inv);
      }
    }
}

// ---------------------------------------------------------------------------
extern "C" void kernel_launch(void* const* d_in, const int* in_sizes, int n_in,
                              void* d_out, int out_size, void* d_ws, size_t ws_size,
                              hipStream_t stream) {
  const float* q  = (const float*)d_in[0];
  const float* k  = (const float*)d_in[1];
  const float* v  = (const float*)d_in[2];
  const float* Wq = (const float*)d_in[3];
  const float* bq = (const float*)d_in[4];
  const float* Wk = (const float*)d_in[5];
  const float* bk = (const float*)d_in[6];
  const float* Wv = (const float*)d_in[7];
  const float* bv = (const float*)d_in[8];
  const float* Wo = (const float*)d_in[9];
  const float* bo = (const float*)d_in[10];
  float* out = (float*)d_out;

  // ws layout: qh | kh | vhT | concat, each 8192*512 bf16 = 8 MB
  unsigned short* qh  = (unsigned short*)d_ws;
  unsigned short* kh  = qh + (size_t)RT * E;
  unsigned short* vhT = kh + (size_t)RT * E;
  unsigned short* cc  = vhT + (size_t)RT * E;

  // 1/sqrt(512) * log2(e): softmax runs in base-2 domain
  const float qscale = 1.4426950408889634f / 22.62741699796952f;

  gemm_nt<float, 0><<<dim3(512), dim3(256), 0, stream>>>(q, Wq, bq, qh, qscale);
  gemm_nt<float, 0><<<dim3(512), dim3(256), 0, stream>>>(k, Wk, bk, kh, 1.0f);
  gemm_nt<float, 2><<<dim3(512), dim3(256), 0, stream>>>(v, Wv, bv, vhT, 1.0f);
  attn_fwd<<<dim3(512), dim3(256), 0, stream>>>(qh, kh, vhT, cc);
  gemm_nt<unsigned short, 1><<<dim3(512), dim3(256), 0, stream>>>(cc, Wo, bo, out, 1.0f);
}

// Round 3
// 195.300 us; speedup vs baseline: 1.9357x; 1.5463x over previous
//
#include <hip/hip_runtime.h>
#include <hip/hip_bf16.h>

#define DEVFN __device__ __forceinline__

typedef __attribute__((ext_vector_type(8))) __bf16 bf16x8;
typedef __attribute__((ext_vector_type(4))) float f32x4;
typedef __attribute__((ext_vector_type(16))) float f32x16;

constexpr int E  = 512;   // embed
constexpr int S  = 4096;  // seq len
constexpr int HD = 64;    // head dim
constexpr int RT = 8192;  // B * S rows

DEVFN unsigned int cvt_pk_bf16(float lo, float hi) {
  unsigned int r;
  asm("v_cvt_pk_bf16_f32 %0, %1, %2" : "=v"(r) : "v"(lo), "v"(hi));
  return r;
}
DEVFN void plswap(unsigned int& a, unsigned int& b) {
  asm("v_permlane32_swap_b32 %0, %1" : "+v"(a), "+v"(b));
}
DEVFN float ex2(float x) { return __builtin_amdgcn_exp2f(x); }

DEVFN unsigned short f2bf(float f) {
  union { float f; unsigned int u; } v; v.f = f;
  unsigned int u = v.u;
  return (unsigned short)((u + 0x7fffu + ((u >> 16) & 1u)) >> 16);
}

DEVFN f32x4 mfma16(bf16x8 a, bf16x8 b, f32x4 c) {
  return __builtin_amdgcn_mfma_f32_16x16x32_bf16(a, b, c, 0, 0, 0);
}
DEVFN f32x16 mfma32(bf16x8 a, bf16x8 b, f32x16 c) {
  return __builtin_amdgcn_mfma_f32_32x32x16_bf16(a, b, c, 0, 0, 0);
}

DEVFN uint4 pk8(const float4& a, const float4& b) {
  uint4 r;
  r.x = cvt_pk_bf16(a.x, a.y); r.y = cvt_pk_bf16(a.z, a.w);
  r.z = cvt_pk_bf16(b.x, b.y); r.w = cvt_pk_bf16(b.z, b.w);
  return r;
}
DEVFN bf16x8 asbf(uint4 u) { union { uint4 a; bf16x8 b; } c; c.a = u; return c.b; }

// ---------------------------------------------------------------------------
// GEMM (NT) body: out[r,n] = (sum_k X[r,k]*W[n,k] + bias[n]) * scale
// Tile 128x64, BK=64, 4 waves as 2x2. Register-prefetched staging (T14),
// fp32->bf16 via v_cvt_pk_bf16_f32.
// OMODE: 0 = bf16 row-major, 1 = f32 row-major, 2 = bf16 transposed per batch
// ---------------------------------------------------------------------------
template<typename TIN, int OMODE>
DEVFN void gemm_body(const TIN* __restrict__ X, const float* __restrict__ W,
                     const float* __restrict__ bias, void* __restrict__ outp,
                     float scale, unsigned short (*Al)[72], unsigned short (*Bl)[72]) {
  const int bid = blockIdx.x;
  const int bm = bid >> 3, bn = bid & 7;
  const int tid = threadIdx.x;
  const int w = tid >> 6, lane = tid & 63;
  const int g = lane >> 4, ln = lane & 15;
  const int wm = w >> 1, wn = w & 1;
  const int r0 = bm * 128, n0 = bn * 64;
  const int arow = tid >> 1, ac0 = (tid & 1) * 32;
  const int brow = tid >> 2, bc0 = (tid & 3) * 16;

  f32x4 acc[4][2] = {};

  float4 af[8];
  uint4  au[4];
  float4 bp[4];

  auto loadA = [&](int k0) {
    if constexpr (sizeof(TIN) == 4) {
      const float* src = (const float*)X + (size_t)(r0 + arow) * E + k0 + ac0;
      #pragma unroll
      for (int i = 0; i < 8; ++i) af[i] = *(const float4*)(src + i * 4);
    } else {
      const unsigned short* src = (const unsigned short*)X + (size_t)(r0 + arow) * E + k0 + ac0;
      #pragma unroll
      for (int i = 0; i < 4; ++i) au[i] = *(const uint4*)(src + i * 8);
    }
  };
  auto loadB = [&](int k0) {
    const float* src = W + (size_t)(n0 + brow) * E + k0 + bc0;
    #pragma unroll
    for (int i = 0; i < 4; ++i) bp[i] = *(const float4*)(src + i * 4);
  };

  loadA(0); loadB(0);

  for (int k0 = 0; k0 < E; k0 += 64) {
    if constexpr (sizeof(TIN) == 4) {
      #pragma unroll
      for (int i = 0; i < 4; ++i)
        *(uint4*)&Al[arow][ac0 + i*8] = pk8(af[2*i], af[2*i+1]);
    } else {
      #pragma unroll
      for (int i = 0; i < 4; ++i)
        *(uint4*)&Al[arow][ac0 + i*8] = au[i];
    }
    *(uint4*)&Bl[brow][bc0]     = pk8(bp[0], bp[1]);
    *(uint4*)&Bl[brow][bc0 + 8] = pk8(bp[2], bp[3]);
    __syncthreads();
    if (k0 + 64 < E) { loadA(k0 + 64); loadB(k0 + 64); }

    #pragma unroll
    for (int kk = 0; kk < 2; ++kk) {
      bf16x8 afr[4], bfr[2];
      #pragma unroll
      for (int i = 0; i < 4; ++i)
        afr[i] = *(const bf16x8*)&Al[wm*64 + i*16 + ln][kk*32 + 8*g];
      #pragma unroll
      for (int j = 0; j < 2; ++j)
        bfr[j] = *(const bf16x8*)&Bl[wn*32 + j*16 + ln][kk*32 + 8*g];
      #pragma unroll
      for (int i = 0; i < 4; ++i)
        #pragma unroll
        for (int j = 0; j < 2; ++j)
          acc[i][j] = mfma16(afr[i], bfr[j], acc[i][j]);
    }
    __syncthreads();
  }

  #pragma unroll
  for (int j = 0; j < 2; ++j) {
    const int gcol = n0 + wn*32 + j*16 + ln;
    const float bv = bias[gcol];
    #pragma unroll
    for (int i = 0; i < 4; ++i) {
      const int gr = r0 + wm*64 + i*16 + 4*g;
      #pragma unroll
      for (int r = 0; r < 4; ++r) {
        const float v = (acc[i][j][r] + bv) * scale;
        if constexpr (OMODE == 1)
          ((float*)outp)[(size_t)(gr + r) * E + gcol] = v;
        else if constexpr (OMODE == 0)
          ((unsigned short*)outp)[(size_t)(gr + r) * E + gcol] = f2bf(v);
        else
          ((unsigned short*)outp)[((size_t)((gr + r) >> 12) * E + gcol) * S + ((gr + r) & (S - 1))] = f2bf(v);
      }
    }
  }
}

__global__ __launch_bounds__(256) void gemm_qkv(const float* __restrict__ q,
    const float* __restrict__ k, const float* __restrict__ v,
    const float* __restrict__ Wq, const float* __restrict__ bq,
    const float* __restrict__ Wk, const float* __restrict__ bk,
    const float* __restrict__ Wv, const float* __restrict__ bv,
    unsigned short* qh, unsigned short* kh, unsigned short* vhT, float qscale) {
  __shared__ unsigned short Al[128][72];
  __shared__ unsigned short Bl[64][72];
  const int y = blockIdx.y;
  if (y == 0)      gemm_body<float, 0>(q, Wq, bq, qh, qscale, Al, Bl);
  else if (y == 1) gemm_body<float, 0>(k, Wk, bk, kh, 1.0f, Al, Bl);
  else             gemm_body<float, 2>(v, Wv, bv, vhT, 1.0f, Al, Bl);
}

__global__ __launch_bounds__(256) void gemm_o(const unsigned short* __restrict__ cc,
    const float* __restrict__ Wo, const float* __restrict__ bo, float* out) {
  __shared__ unsigned short Al[128][72];
  __shared__ unsigned short Bl[64][72];
  gemm_body<unsigned short, 1>(cc, Wo, bo, out, 1.0f, Al, Bl);
}

// ---------------------------------------------------------------------------
// Flash attention, 32x32 MFMA, fully in-register softmax + P redistribution.
// qh pre-scaled by log2(e)/sqrt(512). V arrives transposed (vhT[b][n][s]).
// Block: (b,h,128 q-rows), 4 waves x 32 q. KV tiles of 64.
// QK^T = mfma32(K,Q): col=q=lane&31, t=(reg&3)+8*(reg>>2)+4*(lane>>5)+32*nt.
// PV   = mfma32(V,P): col=q, rows=d -> m/l/rescale per-lane, no shuffles.
// ---------------------------------------------------------------------------
__global__ __launch_bounds__(256) void attn_fwd(const unsigned short* __restrict__ qh,
                                                const unsigned short* __restrict__ kh,
                                                const unsigned short* __restrict__ vhT,
                                                unsigned short* __restrict__ cc) {
  __shared__ unsigned short K_lds[64][72];   // [t][d]
  __shared__ unsigned short V_lds[64][72];   // [d][t]

  const int bid = blockIdx.x;
  const int swz = (bid & 7) * 64 + (bid >> 3);   // XCD-bijective: 2 heads/XCD-L2
  const int bh = swz >> 5, qt = swz & 31;
  const int b = bh >> 3, h = bh & 7;

  const int tid = threadIdx.x;
  const int w = tid >> 6, lane = tid & 63;
  const int l31 = lane & 31, hi = lane >> 5;

  const unsigned short* qb = qh + (size_t)b * S * E + h * HD;
  const unsigned short* kb = kh + (size_t)b * S * E + h * HD;
  const unsigned short* vb = vhT + ((size_t)b * E + h * HD) * S;
  const int q0 = qt * 128 + w * 32;

  // Q as B-operand: q = q0+l31, d = kf*16 + 8*hi + j
  bf16x8 qf[4];
  #pragma unroll
  for (int kf = 0; kf < 4; ++kf)
    qf[kf] = *(const bf16x8*)(qb + (size_t)(q0 + l31) * E + kf*16 + 8*hi);

  f32x16 o0 = {}, o1 = {};
  float ml = -__builtin_inff(), ll = 0.f;

  const int srow = tid >> 2, sc0 = (tid & 3) * 16;
  const unsigned short* kS = kb + (size_t)srow * E + sc0;   // + t0*E
  const unsigned short* vS = vb + (size_t)srow * S + sc0;   // + t0

  uint4 kr0 = *(const uint4*)kS, kr1 = *(const uint4*)(kS + 8);
  uint4 vr0 = *(const uint4*)vS, vr1 = *(const uint4*)(vS + 8);

  for (int it = 0; it < S / 64; ++it) {
    *(uint4*)&K_lds[srow][sc0]     = kr0;
    *(uint4*)&K_lds[srow][sc0 + 8] = kr1;
    *(uint4*)&V_lds[srow][sc0]     = vr0;
    *(uint4*)&V_lds[srow][sc0 + 8] = vr1;
    __syncthreads();

    if (it + 1 < S / 64) {  // async prefetch next tile (T14)
      const unsigned short* kp = kS + (size_t)(it + 1) * 64 * E;
      const unsigned short* vp = vS + (it + 1) * 64;
      kr0 = *(const uint4*)kp; kr1 = *(const uint4*)(kp + 8);
      vr0 = *(const uint4*)vp; vr1 = *(const uint4*)(vp + 8);
    }

    // ---- QK^T ----
    f32x16 s0 = {}, s1 = {};
    __builtin_amdgcn_s_setprio(1);
    #pragma unroll
    for (int kf = 0; kf < 4; ++kf) {
      bf16x8 ka = *(const bf16x8*)&K_lds[l31]     [kf*16 + 8*hi];
      bf16x8 kc = *(const bf16x8*)&K_lds[32 + l31][kf*16 + 8*hi];
      s0 = mfma32(ka, qf[kf], s0);
      s1 = mfma32(kc, qf[kf], s1);
    }
    __builtin_amdgcn_s_setprio(0);

    // ---- online softmax, per-lane (q = l31); halves combined via xor 32 ----
    float tm = -__builtin_inff();
    #pragma unroll
    for (int r = 0; r < 16; ++r) tm = fmaxf(tm, fmaxf(s0[r], s1[r]));
    tm = fmaxf(tm, __shfl_xor(tm, 32));

    if (!__all(tm <= ml + 8.f)) {   // defer-max (T13)
      const float mn = fmaxf(ml, tm);
      const float fr = ex2(ml - mn);
      ml = mn; ll *= fr;
      #pragma unroll
      for (int r = 0; r < 16; ++r) { o0[r] *= fr; o1[r] *= fr; }
    }

    float rs = 0.f;
    #pragma unroll
    for (int r = 0; r < 16; ++r) {
      s0[r] = ex2(s0[r] - ml); rs += s0[r];
      s1[r] = ex2(s1[r] - ml); rs += s1[r];
    }
    rs += __shfl_xor(rs, 32);
    ll += rs;

    // ---- P -> B-frags in-register: cvt_pk + permlane32_swap (T12) ----
    unsigned int a0 = cvt_pk_bf16(s0[0],  s0[1]),  a1 = cvt_pk_bf16(s0[2],  s0[3]);
    unsigned int a2 = cvt_pk_bf16(s0[4],  s0[5]),  a3 = cvt_pk_bf16(s0[6],  s0[7]);
    unsigned int a4 = cvt_pk_bf16(s0[8],  s0[9]),  a5 = cvt_pk_bf16(s0[10], s0[11]);
    unsigned int a6 = cvt_pk_bf16(s0[12], s0[13]), a7 = cvt_pk_bf16(s0[14], s0[15]);
    plswap(a0, a2); plswap(a1, a3); plswap(a4, a6); plswap(a5, a7);
    unsigned int c0 = cvt_pk_bf16(s1[0],  s1[1]),  c1 = cvt_pk_bf16(s1[2],  s1[3]);
    unsigned int c2 = cvt_pk_bf16(s1[4],  s1[5]),  c3 = cvt_pk_bf16(s1[6],  s1[7]);
    unsigned int c4 = cvt_pk_bf16(s1[8],  s1[9]),  c5 = cvt_pk_bf16(s1[10], s1[11]);
    unsigned int c6 = cvt_pk_bf16(s1[12], s1[13]), c7 = cvt_pk_bf16(s1[14], s1[15]);
    plswap(c0, c2); plswap(c1, c3); plswap(c4, c6); plswap(c5, c7);
    uint4 pa[4];
    pa[0] = uint4{a0, a1, a2, a3};  // t  0..15
    pa[1] = uint4{a4, a5, a6, a7};  // t 16..31
    pa[2] = uint4{c0, c1, c2, c3};  // t 32..47
    pa[3] = uint4{c4, c5, c6, c7};  // t 48..63

    // ---- O += V^T x P : mfma32(V_frag{rows d}, P_frag{rows q}) ----
    __builtin_amdgcn_s_setprio(1);
    #pragma unroll
    for (int tf = 0; tf < 4; ++tf) {
      bf16x8 va = *(const bf16x8*)&V_lds[l31]     [tf*16 + 8*hi];
      bf16x8 vc = *(const bf16x8*)&V_lds[32 + l31][tf*16 + 8*hi];
      bf16x8 pf = asbf(pa[tf]);
      o0 = mfma32(va, pf, o0);
      o1 = mfma32(vc, pf, o1);
    }
    __builtin_amdgcn_s_setprio(0);
    __syncthreads();
  }

  // ---- epilogue: d = (r&3)+8*(r>>2)+4*hi (+32 for o1), col q = l31 ----
  const float inv = 1.0f / ll;
  const size_t rowb = (size_t)(b * S + q0 + l31) * E + h * HD;
  #pragma unroll
  for (int qd = 0; qd < 4; ++qd) {
    uint2 w0, w1;
    w0.x = cvt_pk_bf16(o0[4*qd]     * inv, o0[4*qd + 1] * inv);
    w0.y = cvt_pk_bf16(o0[4*qd + 2] * inv, o0[4*qd + 3] * inv);
    *(uint2*)&cc[rowb + 8*qd + 4*hi] = w0;
    w1.x = cvt_pk_bf16(o1[4*qd]     * inv, o1[4*qd + 1] * inv);
    w1.y = cvt_pk_bf16(o1[4*qd + 2] * inv, o1[4*qd + 3] * inv);
    *(uint2*)&cc[rowb + 32 + 8*qd + 4*hi] = w1;
  }
}

// ---------------------------------------------------------------------------
extern "C" void kernel_launch(void* const* d_in, const int* in_sizes, int n_in,
                              void* d_out, int out_size, void* d_ws, size_t ws_size,
                              hipStream_t stream) {
  const float* q  = (const float*)d_in[0];
  const float* k  = (const float*)d_in[1];
  const float* v  = (const float*)d_in[2];
  const float* Wq = (const float*)d_in[3];
  const float* bq = (const float*)d_in[4];
  const float* Wk = (const float*)d_in[5];
  const float* bk = (const float*)d_in[6];
  const float* Wv = (const float*)d_in[7];
  const float* bv = (const float*)d_in[8];
  const float* Wo = (const float*)d_in[9];
  const float* bo = (const float*)d_in[10];
  float* out = (float*)d_out;

  unsigned short* qh  = (unsigned short*)d_ws;
  unsigned short* kh  = qh + (size_t)RT * E;
  unsigned short* vhT = kh + (size_t)RT * E;
  unsigned short* cc  = vhT + (size_t)RT * E;

  // 1/sqrt(512) * log2(e): softmax runs in base-2 domain
  const float qscale = 1.4426950408889634f / 22.62741699796952f;

  gemm_qkv<<<dim3(512, 3), dim3(256), 0, stream>>>(q, k, v, Wq, bq, Wk, bk, Wv, bv,
                                                   qh, kh, vhT, qscale);
  attn_fwd<<<dim3(512), dim3(256), 0, stream>>>(qh, kh, vhT, cc);
  gemm_o<<<dim3(512), dim3(256), 0, stream>>>(cc, Wo, bo, out);
}